// Round 8
// baseline (415.944 us; speedup 1.0000x reference)
//
#include <hip/hip_runtime.h>
#include <hip/hip_bf16.h>

// ---------------------------------------------------------------------------
// HoRA linear: out = x @ (base_w + (150*ifft2(sparse_spectrum)) @ A)^T + b
// M=8192, N=4096, K=4096.  bf16 MFMA GEMM with f32 accumulate.
// GEMM: 256x256 tile, BK=64, 8 waves, mfma_f32_32x32x16_bf16 with
// conflict-free swizzle g(row)=(row>>2)&7 (2-way, free), uniform m201
// stage rotation, vmcnt(2) at P4/P8 only, zero post-barrier reads.
// ---------------------------------------------------------------------------

#define OUTF 4096
#define INF  4096
#define NFREQ 10000
#define MDIM 8192
#define KT   (INF / 64)

typedef __attribute__((ext_vector_type(8)))  short bf16x8;
typedef __attribute__((ext_vector_type(16))) float f32x16;

__device__ __forceinline__ unsigned int bf16pack2(float a, float b) {
    unsigned int ua = __builtin_bit_cast(unsigned int, a);
    unsigned int ub = __builtin_bit_cast(unsigned int, b);
    ua = (ua + 0x7fffu + ((ua >> 16) & 1u)) >> 16;          // RNE
    ub = (ub + 0x7fffu + ((ub >> 16) & 1u)) & 0xffff0000u;  // RNE, keep high
    return ua | ub;
}

__device__ __forceinline__ void async_copy16(const void* g, void* l) {
    __builtin_amdgcn_global_load_lds(
        (__attribute__((address_space(1))) void*)(g),
        (__attribute__((address_space(3))) void*)(l),
        16, 0, 0);
}

// ---------------------------------------------------------------------------
// Kernel 1a: compact nnz per chunk (4 blocks, deterministic ballot prefix).
// ---------------------------------------------------------------------------
__global__ __launch_bounds__(256) void compact_kernel(
        const float* __restrict__ spectrum, const int* __restrict__ idx,
        int2* __restrict__ cjk, int* __restrict__ ccnt) {
    const int p   = blockIdx.x;          // chunk 0..3
    const int tid = threadIdx.x;
    const int wv  = tid >> 6, ln = tid & 63;
    __shared__ int wcnt[4];
    int cnt = 0;
    for (int i0 = wv * 64; i0 < NFREQ; i0 += 256) {
        const int i = i0 + ln;
        bool m = (i < NFREQ) && ((idx[i] >> 14) == p);
        cnt += __popcll(__ballot(m));
    }
    if (ln == 0) wcnt[wv] = cnt;
    __syncthreads();
    int base = 0;
    for (int w = 0; w < wv; ++w) base += wcnt[w];
    for (int i0 = wv * 64; i0 < NFREQ; i0 += 256) {
        const int i = i0 + ln;
        bool m = false; int id = 0;
        if (i < NFREQ) { id = idx[i]; m = ((id >> 14) == p); }
        unsigned long long bal = __ballot(m);
        if (m) {
            int pos = base + __popcll(bal & ((1ull << ln) - 1ull));
            if (pos < 4096)
                cjk[p * 4096 + pos] =
                    make_int2(id & 16383, __builtin_bit_cast(int, spectrum[i]));
        }
        base += __popcll(bal);
    }
    if (tid == 0) {
        int t = wcnt[0] + wcnt[1] + wcnt[2] + wcnt[3];
        ccnt[p] = (t < 4096) ? t : 4096;
    }
}

// ---------------------------------------------------------------------------
// Kernel 1b: B[o][r] = (150/16384)*sum_nnz val*cos(2*pi*phase/16384)
// + fused grid-stride x(f32)->bf16 conversion (overlaps VALU with streaming).
// ---------------------------------------------------------------------------
__global__ __launch_bounds__(256) void buildB_cvt_kernel(
        const int2* __restrict__ cjk, const int* __restrict__ ccnt,
        float* __restrict__ Bout,
        const float4* __restrict__ x4, uint2* __restrict__ xb) {
    __shared__ int2  s_jkv[4096];
    __shared__ float s_part[4][64];
    const int tid  = threadIdx.x;
    const int gid0 = blockIdx.x * 64;
    const int p    = gid0 >> 14;
    const int cnt  = ccnt[p];
    for (int t = tid; t < cnt; t += 256) s_jkv[t] = cjk[p * 4096 + t];
    __syncthreads();
    const int qtr  = tid >> 6;
    const int ol   = tid & 63;
    const int gid  = gid0 + ol;
    const int o    = gid >> 4;
    const int r    = gid & 15;
    const int m    = o & 1023;
    const int qlen = (cnt + 3) >> 2;
    const int t0   = qtr * qlen;
    const int t1   = (t0 + qlen < cnt) ? t0 + qlen : cnt;
    const float c  = 6.283185307179586f / 16384.f;
    float acc = 0.f;
    for (int t = t0; t < t1; ++t) {
        const int2 jv = s_jkv[t];
        const int j = jv.x >> 4, k = jv.x & 15;
        int ph = (((j * m) & 1023) << 4) + (((k * r) & 15) << 10);
        acc += __builtin_bit_cast(float, jv.y) * __cosf((float)(ph & 16383) * c);
    }
    s_part[qtr][ol] = acc;
    __syncthreads();
    if (tid < 64) {
        float s = s_part[0][tid] + s_part[1][tid] + s_part[2][tid] + s_part[3][tid];
        Bout[gid0 + tid] = s * (150.f / 16384.f);
    }
    // ---- fused x -> bf16 (independent of B computation) ----
    const int n4 = (MDIM * INF) / 4;
    for (int i = blockIdx.x * 256 + tid; i < n4; i += 1024 * 256) {
        float4 v = x4[i];
        xb[i] = make_uint2(bf16pack2(v.x, v.y), bf16pack2(v.z, v.w));
    }
}

// ---------------------------------------------------------------------------
// Kernel 2: W_bf16[n][k] = bf16(base_w[n][k] + sum_r Bs[n][r] * A[r][k])
// ---------------------------------------------------------------------------
__global__ __launch_bounds__(256) void build_w_kernel(
        const float* __restrict__ bw, const float* __restrict__ A,
        const float* __restrict__ Bs, unsigned short* __restrict__ W) {
    const int n0 = blockIdx.x * 8;
    __shared__ float sB[8][16];
    if (threadIdx.x < 128)
        ((float*)sB)[threadIdx.x] = Bs[n0 * 16 + threadIdx.x];
    __syncthreads();
    const float4* A4 = (const float4*)A;
    const float4* bw4 = (const float4*)bw;
    uint2* W2 = (uint2*)W;
#pragma unroll 1
    for (int q = 0; q < 4; ++q) {
        const int c4 = threadIdx.x + q * 256;
        float4 a[16];
#pragma unroll
        for (int r = 0; r < 16; ++r) a[r] = A4[r * 1024 + c4];
#pragma unroll 1
        for (int nn = 0; nn < 8; ++nn) {
            const int n = n0 + nn;
            float4 wv = bw4[n * 1024 + c4];
#pragma unroll
            for (int r = 0; r < 16; ++r) {
                float s = sB[nn][r];
                wv.x += s * a[r].x; wv.y += s * a[r].y;
                wv.z += s * a[r].z; wv.w += s * a[r].w;
            }
            W2[n * 1024 + c4] = make_uint2(bf16pack2(wv.x, wv.y),
                                           bf16pack2(wv.z, wv.w));
        }
    }
}

// ---------------------------------------------------------------------------
// Kernel 3: 256x256-tile 8-wave bf16 GEMM, mfma_f32_32x32x16_bf16.
// Per wave: 128x64 out = 4(f) x 2(n) frags of 32x32 (16 f32 acc each).
// Swizzle: physical 16B-slot = logical ^ ((row>>2)&7)  [2-way, free: within
// each lane&3 class of 16 lanes, (l>>2)&7 spans all 8 slots].
// Phases (E in buf0, O in buf1; quadrant Q(fh,n) = 8 MFMA over ks=0..3):
//  P1 E.Q(0,0) [bfa+af01: 12 rd] stage A0(O)      P5 O.Q(0,0)  stage A0(E+2)
//  P2 E.Q(0,1) [bfb: 4 rd]       stage A1(O)      P6 O.Q(0,1)  stage A1(E+2)
//  P3 E.Q(1,0) [af23: 8 rd]      stage B0(E+2)    P7 O.Q(1,0)  stage B0(E+3)
//  P4 E.Q(1,1) [0 rd] stage B1(E+2); vmcnt(2)     P8 O.Q(1,1)  stage B1(E+3); vmcnt(2)
// Ledger: A regions last read at Qx(1,0) phase -> restaged 2 phases later;
// B last read at Q(0,1) -> restaged next phase; vmcnt(2)@P4 retires A(O),
// vmcnt(2)@P8 retires tile E+2 (leaves B(E+3) in flight). All reads pre-
// barrier from regions retired >=1 vmcnt+barrier earlier.
// ---------------------------------------------------------------------------
__global__ __launch_bounds__(512, 2) void gemm256_kernel(
        const unsigned short* __restrict__ Xb,
        const unsigned short* __restrict__ Wb,
        const float* __restrict__ bias, float* __restrict__ C) {
    __shared__ __align__(1024) char lds[131072];

    const int tid  = threadIdx.x;
    const int lane = tid & 63;
    const int wid  = tid >> 6;
    const int wm   = wid >> 2;   // 0..1
    const int wn   = wid & 3;    // 0..3

    // XCD-bijective swizzle: nwg=512, divisible by 8.
    int bid = blockIdx.x;
    bid = (bid & 7) * 64 + (bid >> 3);
    const int tm = bid >> 4;     // 0..31  M tile
    const int tn = bid & 15;     // 0..15  N tile
    const int arow0 = tm * 256;
    const int brow0 = tn * 256;

    // staging: thread covers rows srow, srow+64 of a 128-row half.
    // source col pre-swizzled with g = (row>>2)&7 = (tid>>5)&7 (row=tid>>3).
    const int scole = (((tid & 7) << 4) ^ (((tid >> 5) & 7) << 4)) >> 1;
    const int srow  = tid >> 3;
    const int sldsb = tid * 16;

    // fragment reads (32x32x16): row = base + (lane&31);
    // logical slot = 2*ks + (lane>>5); physical = logical ^ ((l31>>2)&7).
    const int l31 = lane & 31;
    const int kxr = ((lane >> 5) << 4) ^ (((l31 >> 2) & 7) << 4);
    const int abase = (wm * 128 + l31) * 128;            // + f*4096
    const int bbase = 32768 + (wn * 64 + l31) * 128;     // + n*4096

    f32x16 acc[4][2] = {};
    bf16x8 af[2][4], bfa[4], bfb[4];

#define BUF_E 0
#define BUF_O 65536

#define STAGE_HALF(mat, grow0, t, ldsbase) do {                               \
        const unsigned short* _s =                                            \
            (mat) + ((grow0) + srow) * INF + (t) * 64 + scole;                \
        async_copy16(_s, lds + (ldsbase) + sldsb);                            \
        async_copy16(_s + 64 * INF, lds + (ldsbase) + 8192 + sldsb);          \
    } while (0)

#define LDA(DB, f, ks) (*(const bf16x8*)(lds + (DB) + abase + (f) * 4096 + (((ks) << 5) ^ kxr)))
#define LDB(DB, n, ks) (*(const bf16x8*)(lds + (DB) + bbase + (n) * 4096 + (((ks) << 5) ^ kxr)))
#define MFMA(a, b, c) __builtin_amdgcn_mfma_f32_32x32x16_bf16((a), (b), (c), 0, 0, 0)
#define BARRIER() do { asm volatile("" ::: "memory");                         \
                       __builtin_amdgcn_s_barrier();                          \
                       asm volatile("" ::: "memory"); } while (0)
#define PH_SYNC() do { BARRIER();                                             \
                       asm volatile("s_waitcnt lgkmcnt(0)" ::: "memory");     \
                       __builtin_amdgcn_sched_barrier(0); } while (0)

#define RD_BFA(DB)  _Pragma("unroll") for (int ks = 0; ks < 4; ++ks)          \
                        bfa[ks] = LDB(DB, 0, ks);
#define RD_BFB(DB)  _Pragma("unroll") for (int ks = 0; ks < 4; ++ks)          \
                        bfb[ks] = LDB(DB, 1, ks);
#define RD_AF01(DB) _Pragma("unroll") for (int j = 0; j < 2; ++j)             \
                        _Pragma("unroll") for (int ks = 0; ks < 4; ++ks)      \
                            af[j][ks] = LDA(DB, j, ks);
#define RD_AF23(DB) _Pragma("unroll") for (int j = 0; j < 2; ++j)             \
                        _Pragma("unroll") for (int ks = 0; ks < 4; ++ks)      \
                            af[j][ks] = LDA(DB, j + 2, ks);

#define QMFMA(fh, n, B)                                                       \
    __builtin_amdgcn_s_setprio(1);                                            \
    _Pragma("unroll") for (int ks = 0; ks < 4; ++ks)                          \
        _Pragma("unroll") for (int j = 0; j < 2; ++j)                         \
            acc[(fh) * 2 + j][n] =                                            \
                MFMA(af[j][ks], (B)[ks], acc[(fh) * 2 + j][n]);               \
    __builtin_amdgcn_s_setprio(0)

#define PAIR(s) do {                                                          \
    /* P1: E.Q(0,0); stage A0(O) */                                           \
    RD_BFA(BUF_E); RD_AF01(BUF_E);                                            \
    STAGE_HALF(Xb, arow0,       (s) + 1, BUF_O + 0);                          \
    PH_SYNC(); QMFMA(0, 0, bfa); BARRIER();                                   \
    /* P2: E.Q(0,1); stage A1(O) */                                           \
    RD_BFB(BUF_E);                                                            \
    STAGE_HALF(Xb, arow0 + 128, (s) + 1, BUF_O + 16384);                      \
    PH_SYNC(); QMFMA(0, 1, bfb); BARRIER();                                   \
    /* P3: E.Q(1,0); stage B0(E+2) */                                         \
    RD_AF23(BUF_E);                                                           \
    if ((s) + 2 < KT) STAGE_HALF(Wb, brow0, (s) + 2, BUF_E + 32768);          \
    PH_SYNC(); QMFMA(1, 0, bfa); BARRIER();                                   \
    /* P4: E.Q(1,1); stage B1(E+2); vmcnt(2) */                               \
    if ((s) + 2 < KT) STAGE_HALF(Wb, brow0 + 128, (s) + 2, BUF_E + 49152);    \
    PH_SYNC(); QMFMA(1, 1, bfb);                                              \
    if ((s) + 2 < KT) { asm volatile("s_waitcnt vmcnt(2)" ::: "memory"); }    \
    else              { asm volatile("s_waitcnt vmcnt(0)" ::: "memory"); }    \
    BARRIER();                                                                \
    /* P5: O.Q(0,0); stage A0(E+2) */                                         \
    RD_BFA(BUF_O); RD_AF01(BUF_O);                                            \
    if ((s) + 2 < KT) STAGE_HALF(Xb, arow0, (s) + 2, BUF_E + 0);              \
    PH_SYNC(); QMFMA(0, 0, bfa); BARRIER();                                   \
    /* P6: O.Q(0,1); stage A1(E+2) */                                         \
    RD_BFB(BUF_O);                                                            \
    if ((s) + 2 < KT) STAGE_HALF(Xb, arow0 + 128, (s) + 2, BUF_E + 16384);    \
    PH_SYNC(); QMFMA(0, 1, bfb); BARRIER();                                   \
    /* P7: O.Q(1,0); stage B0(E+3) */                                         \
    RD_AF23(BUF_O);                                                           \
    if ((s) + 3 < KT) STAGE_HALF(Wb, brow0, (s) + 3, BUF_O + 32768);          \
    PH_SYNC(); QMFMA(1, 0, bfa); BARRIER();                                   \
    /* P8: O.Q(1,1); stage B1(E+3); vmcnt(2) */                               \
    if ((s) + 3 < KT) STAGE_HALF(Wb, brow0 + 128, (s) + 3, BUF_O + 49152);    \
    PH_SYNC(); QMFMA(1, 1, bfb);                                              \
    if ((s) + 3 < KT) { asm volatile("s_waitcnt vmcnt(2)" ::: "memory"); }    \
    else              { asm volatile("s_waitcnt vmcnt(0)" ::: "memory"); }    \
    BARRIER();                                                                \
} while (0)

    // ---- prologue: tile0 fully + B(1); drain; barrier ----
    STAGE_HALF(Wb, brow0,       0, BUF_E + 32768);
    STAGE_HALF(Wb, brow0 + 128, 0, BUF_E + 49152);
    STAGE_HALF(Xb, arow0,       0, BUF_E + 0);
    STAGE_HALF(Xb, arow0 + 128, 0, BUF_E + 16384);
    STAGE_HALF(Wb, brow0,       1, BUF_O + 32768);
    STAGE_HALF(Wb, brow0 + 128, 1, BUF_O + 49152);
    asm volatile("s_waitcnt vmcnt(0)" ::: "memory");
    BARRIER();

    for (int s = 0; s < KT; s += 2)
        PAIR(s);

    // ---- epilogue: C = acc + bias ----
    // 32x32 C layout: col = lane&31, row = (reg&3) + 8*(reg>>2) + 4*(lane>>5)
#pragma unroll
    for (int n = 0; n < 2; ++n) {
        const int gcol = brow0 + wn * 64 + n * 32 + l31;
        const float bv = bias[gcol];
#pragma unroll
        for (int f = 0; f < 4; ++f) {
            const int rbase = arow0 + wm * 128 + f * 32 + 4 * (lane >> 5);
#pragma unroll
            for (int reg = 0; reg < 16; ++reg) {
                const int grow = rbase + (reg & 3) + 8 * (reg >> 2);
                C[grow * OUTF + gcol] = acc[f][n][reg] + bv;
            }
        }
    }
#undef STAGE_HALF
#undef LDA
#undef LDB
#undef MFMA
#undef BARRIER
#undef PH_SYNC
#undef RD_BFA
#undef RD_BFB
#undef RD_AF01
#undef RD_AF23
#undef QMFMA
#undef PAIR
#undef BUF_E
#undef BUF_O
}

// ---------------------------------------------------------------------------
extern "C" void kernel_launch(void* const* d_in, const int* in_sizes, int n_in,
                              void* d_out, int out_size, void* d_ws, size_t ws_size,
                              hipStream_t stream) {
    const float* x    = (const float*)d_in[0];   // [4,2048,4096]
    const float* bw   = (const float*)d_in[1];   // [4096,4096]
    const float* bb   = (const float*)d_in[2];   // [4096]
    const float* spec = (const float*)d_in[3];   // [10000]
    const float* ha   = (const float*)d_in[4];   // [16,4096]
    const int*   idx  = (const int*)d_in[5];     // [10000]
    float* out = (float*)d_out;

    char* ws = (char*)d_ws;
    float*          Bbuf = (float*)ws;                                // 256 KB
    unsigned short* Wb   = (unsigned short*)(ws + 262144);            // 32 MB
    unsigned short* Xb   = (unsigned short*)(ws + 262144 + 33554432); // 64 MB
    int2*           cjk  = (int2*)(ws + 262144 + 33554432 + 67108864);// 128 KB
    int*            ccnt = (int*)(ws + 262144 + 33554432 + 67108864 + 131072);

    compact_kernel<<<4, 256, 0, stream>>>(spec, idx, cjk, ccnt);
    buildB_cvt_kernel<<<1024, 256, 0, stream>>>(cjk, ccnt, Bbuf,
                                                (const float4*)x, (uint2*)Xb);
    build_w_kernel<<<512, 256, 0, stream>>>(bw, ha, Bbuf, Wb);
    gemm256_kernel<<<512, 512, 0, stream>>>(Xb, Wb, bb, out);
}

// Round 9
// 388.141 us; speedup vs baseline: 1.0716x; 1.0716x over previous
//
#include <hip/hip_runtime.h>
#include <hip/hip_bf16.h>

// ---------------------------------------------------------------------------
// HoRA linear: out = x @ (base_w + (150*ifft2(sparse_spectrum)) @ A)^T + b
// M=8192, N=4096, K=4096.  bf16 MFMA GEMM with f32 accumulate.
// GEMM: r7-proven 256x256 8-wave 8-phase 16x16x32 kernel (245us, 0 conflicts).
// Prep: 2-stage FFT factorization for B (16x fewer transcendentals),
// k-sorted nnz buckets, fused x->bf16 tail.
// ---------------------------------------------------------------------------

#define OUTF 4096
#define INF  4096
#define NFREQ 10000
#define MDIM 8192
#define KT   (INF / 64)

typedef __attribute__((ext_vector_type(8))) short bf16x8;
typedef __attribute__((ext_vector_type(4))) float f32x4;

__device__ __forceinline__ unsigned int bf16pack2(float a, float b) {
    unsigned int ua = __builtin_bit_cast(unsigned int, a);
    unsigned int ub = __builtin_bit_cast(unsigned int, b);
    ua = (ua + 0x7fffu + ((ua >> 16) & 1u)) >> 16;          // RNE
    ub = (ub + 0x7fffu + ((ub >> 16) & 1u)) & 0xffff0000u;  // RNE, keep high
    return ua | ub;
}

__device__ __forceinline__ void async_copy16(const void* g, void* l) {
    __builtin_amdgcn_global_load_lds(
        (__attribute__((address_space(1))) void*)(g),
        (__attribute__((address_space(3))) void*)(l),
        16, 0, 0);
}

// ---------------------------------------------------------------------------
// Kernel 1: per chunk p: compact nnz, then deterministic counting-sort by k.
// cjk2[p*4096 + pos] = (j, bits(val)) sorted by k; boff[p*17 + k] = bucket
// start, boff[p*17+16] = count.  4 blocks x 256 thr; ballot-prefix only.
// ---------------------------------------------------------------------------
__global__ __launch_bounds__(256) void compact_sort_kernel(
        const float* __restrict__ spectrum, const int* __restrict__ idx,
        int2* __restrict__ cjk2, int* __restrict__ boff) {
    const int p   = blockIdx.x;          // chunk 0..3
    const int tid = threadIdx.x;
    const int wv  = tid >> 6, ln = tid & 63;
    __shared__ int2 s_list[4096];
    __shared__ int  wcnt[4];
    __shared__ int  s_cnt;
    __shared__ int  kcnt[16];
    __shared__ int  kbase[17];
    // ---- pass 1: per-wave counts ----
    int cnt = 0;
    for (int i0 = wv * 64; i0 < NFREQ; i0 += 256) {
        const int i = i0 + ln;
        bool m = (i < NFREQ) && ((idx[i] >> 14) == p);
        cnt += __popcll(__ballot(m));
    }
    if (ln == 0) wcnt[wv] = cnt;
    __syncthreads();
    int base = 0;
    for (int w = 0; w < wv; ++w) base += wcnt[w];
    // ---- pass 2: compact into LDS (original order) ----
    for (int i0 = wv * 64; i0 < NFREQ; i0 += 256) {
        const int i = i0 + ln;
        bool m = false; int id = 0;
        if (i < NFREQ) { id = idx[i]; m = ((id >> 14) == p); }
        unsigned long long bal = __ballot(m);
        if (m) {
            int pos = base + __popcll(bal & ((1ull << ln) - 1ull));
            if (pos < 4096)
                s_list[pos] = make_int2(id & 16383,
                                        __builtin_bit_cast(int, spectrum[i]));
        }
        base += __popcll(bal);
    }
    if (tid == 0) {
        int t = wcnt[0] + wcnt[1] + wcnt[2] + wcnt[3];
        s_cnt = (t < 4096) ? t : 4096;
    }
    __syncthreads();
    const int n = s_cnt;
    // ---- count per k (wave wv handles k = wv*4+q) ----
    for (int q = 0; q < 4; ++q) {
        const int k = wv * 4 + q;
        int c = 0;
        for (int t0 = 0; t0 < n; t0 += 64) {
            const int t = t0 + ln;
            bool m = (t < n) && ((s_list[t].x & 15) == k);
            c += __popcll(__ballot(m));
        }
        if (ln == 0) kcnt[k] = c;
    }
    __syncthreads();
    if (tid == 0) {
        int a = 0;
        for (int k = 0; k < 16; ++k) { kbase[k] = a; a += kcnt[k]; }
        kbase[16] = a;
    }
    __syncthreads();
    // ---- stable write into k-buckets ----
    for (int q = 0; q < 4; ++q) {
        const int k = wv * 4 + q;
        int b2 = kbase[k];
        for (int t0 = 0; t0 < n; t0 += 64) {
            const int t = t0 + ln;
            bool m = (t < n) && ((s_list[t].x & 15) == k);
            unsigned long long bal = __ballot(m);
            if (m) {
                int pos = b2 + __popcll(bal & ((1ull << ln) - 1ull));
                cjk2[p * 4096 + pos] = make_int2(s_list[t].x >> 4, s_list[t].y);
            }
            b2 += __popcll(bal);
        }
    }
    if (tid < 17) boff[p * 17 + tid] = kbase[tid];
}

// ---------------------------------------------------------------------------
// Kernel 2: B via 2-stage IFFT factorization + fused x->bf16 tail.
// Blocks 0..255: (p = b>>6, mblk = b&63); threads (m_loc=tid>>4, k=tid&15).
// stage1: S1[m][k] = sum_{j in bucket(p,k)} v * e^{+2pi i (j*m mod 1024)/1024}
// stage2: B[o][r]  = (150/16384) * sum_k Re(S1[m][k] * e^{+2pi i (k*r)/16})
// All 2048 blocks: grid-stride x f32->bf16.
// ---------------------------------------------------------------------------
__global__ __launch_bounds__(256) void buildB_cvt_kernel(
        const int2* __restrict__ cjk2, const int* __restrict__ boff,
        float* __restrict__ Bout,
        const float4* __restrict__ x4, uint2* __restrict__ xb) {
    __shared__ int2  s_jv[4096];
    __shared__ float s1re[16][16];
    __shared__ float s1im[16][17];
    if (blockIdx.x < 256) {
        const int tid  = threadIdx.x;
        const int p    = blockIdx.x >> 6;
        const int mblk = blockIdx.x & 63;
        const int cnt  = boff[p * 17 + 16];
        for (int t = tid; t < cnt; t += 256) s_jv[t] = cjk2[p * 4096 + t];
        __syncthreads();
        const int m_loc = tid >> 4;
        const int k     = tid & 15;
        const int m     = mblk * 16 + m_loc;
        const int kb0   = boff[p * 17 + k];
        const int kb1   = boff[p * 17 + k + 1];
        const float c1  = 6.283185307179586f / 1024.f;
        float re = 0.f, im = 0.f;
        for (int t = kb0; t < kb1; ++t) {
            const int2 jv = s_jv[t];
            const float v = __builtin_bit_cast(float, jv.y);
            const float ang = (float)((jv.x * m) & 1023) * c1;
            re += v * __cosf(ang);
            im += v * __sinf(ang);
        }
        s1re[m_loc][k] = re;
        s1im[m_loc][k] = im;
        __syncthreads();
        // stage2: thread (m_loc, r = k slot)
        const int r = k;
        const float c2 = 6.283185307179586f / 16.f;
        float b = 0.f;
#pragma unroll
        for (int k2 = 0; k2 < 16; ++k2) {
            const float ang = (float)((k2 * r) & 15) * c2;
            b += s1re[m_loc][k2] * __cosf(ang) - s1im[m_loc][k2] * __sinf(ang);
        }
        const int o = p * 1024 + m;
        Bout[o * 16 + r] = b * (150.f / 16384.f);
    }
    // ---- fused x -> bf16 (all 2048 blocks) ----
    const int n4 = (MDIM * INF) / 4;
    for (int i = blockIdx.x * 256 + threadIdx.x; i < n4; i += 2048 * 256) {
        float4 v = x4[i];
        xb[i] = make_uint2(bf16pack2(v.x, v.y), bf16pack2(v.z, v.w));
    }
}

// ---------------------------------------------------------------------------
// Kernel 3: W_bf16[n][k] = bf16(base_w[n][k] + sum_r Bs[n][r] * A[r][k])
// ---------------------------------------------------------------------------
__global__ __launch_bounds__(256) void build_w_kernel(
        const float* __restrict__ bw, const float* __restrict__ A,
        const float* __restrict__ Bs, unsigned short* __restrict__ W) {
    const int n0 = blockIdx.x * 8;
    __shared__ float sB[8][16];
    if (threadIdx.x < 128)
        ((float*)sB)[threadIdx.x] = Bs[n0 * 16 + threadIdx.x];
    __syncthreads();
    const float4* A4 = (const float4*)A;
    const float4* bw4 = (const float4*)bw;
    uint2* W2 = (uint2*)W;
#pragma unroll 1
    for (int q = 0; q < 4; ++q) {
        const int c4 = threadIdx.x + q * 256;
        float4 a[16];
#pragma unroll
        for (int r = 0; r < 16; ++r) a[r] = A4[r * 1024 + c4];
#pragma unroll 1
        for (int nn = 0; nn < 8; ++nn) {
            const int n = n0 + nn;
            float4 wv = bw4[n * 1024 + c4];
#pragma unroll
            for (int r = 0; r < 16; ++r) {
                float s = sB[nn][r];
                wv.x += s * a[r].x; wv.y += s * a[r].y;
                wv.z += s * a[r].z; wv.w += s * a[r].w;
            }
            W2[n * 1024 + c4] = make_uint2(bf16pack2(wv.x, wv.y),
                                           bf16pack2(wv.z, wv.w));
        }
    }
}

// ---------------------------------------------------------------------------
// Kernel 4: r7-proven 256x256-tile 8-wave bf16 GEMM, 8-phase/2-K-tile.
// (verbatim from round 7: 245us, MfmaUtil 50.9, 0 bank conflicts)
// ---------------------------------------------------------------------------
__global__ __launch_bounds__(512, 2) void gemm256_kernel(
        const unsigned short* __restrict__ Xb,
        const unsigned short* __restrict__ Wb,
        const float* __restrict__ bias, float* __restrict__ C) {
    __shared__ __align__(1024) char lds[131072];

    const int tid  = threadIdx.x;
    const int lane = tid & 63;
    const int wid  = tid >> 6;
    const int wm   = wid >> 2;   // 0..1
    const int wn   = wid & 3;    // 0..3

    // XCD-bijective swizzle: nwg=512, divisible by 8.
    int bid = blockIdx.x;
    bid = (bid & 7) * 64 + (bid >> 3);
    const int tm = bid >> 4;     // 0..31  M tile
    const int tn = bid & 15;     // 0..15  N tile
    const int arow0 = tm * 256;
    const int brow0 = tn * 256;

    // staging: thread covers rows srow, srow+64 of a 128-row half, 16B chunk.
    const int srow  = tid >> 3;
    const int scole = (((tid & 7) * 16) ^ ((srow & 7) << 4)) >> 1;
    const int sldsb = tid * 16;

    // fragment reads (proven conflict-free pattern): row = base + (lane&15).
    const int l15 = lane & 15;
    const int kx0 = ((lane >> 4) * 16) ^ ((lane & 7) << 4);
    const int kx1 = kx0 ^ 64;
    const int abase0 = (wm * 128 + l15) * 128;
    const int bbase0 = 32768 + (wn * 64 + l15) * 128;

    f32x4 acc[8][4] = {};
    bf16x8 af[4][2], bfa[2][2], bfb[2][2];

#define STAGE_HALF(mat, grow0, t, ldsbase) do {                               \
        const unsigned short* _s =                                            \
            (mat) + ((grow0) + srow) * INF + (t) * 64 + scole;                \
        async_copy16(_s, lds + (ldsbase) + sldsb);                            \
        async_copy16(_s + 64 * INF, lds + (ldsbase) + 8192 + sldsb);          \
    } while (0)

#define LDA(DB, m, kh) (*(const bf16x8*)(lds + (DB) + abase0 + (m) * 2048 + ((kh) ? kx1 : kx0)))
#define LDB(DB, n, kh) (*(const bf16x8*)(lds + (DB) + bbase0 + (n) * 2048 + ((kh) ? kx1 : kx0)))
#define MFMA(a, b, c) __builtin_amdgcn_mfma_f32_16x16x32_bf16((a), (b), (c), 0, 0, 0)
#define BARRIER() do { asm volatile("" ::: "memory");                         \
                       __builtin_amdgcn_s_barrier();                          \
                       asm volatile("" ::: "memory"); } while (0)
#define LGKM0()  asm volatile("s_waitcnt lgkmcnt(0)" ::: "memory")

#define QMFMA(mh, BF)                                                         \
    __builtin_amdgcn_s_setprio(1);                                            \
    _Pragma("unroll") for (int ks = 0; ks < 2; ++ks)                          \
        _Pragma("unroll") for (int m = 0; m < 4; ++m)                         \
            _Pragma("unroll") for (int n = 0; n < 2; ++n)                     \
                acc[(mh) * 4 + m][(BF) * 2 + n] =                             \
                    MFMA(af[m][ks], ((BF) ? bfb : bfa)[n][ks],                \
                         acc[(mh) * 4 + m][(BF) * 2 + n]);                    \
    __builtin_amdgcn_s_setprio(0)

#define RD_AF(DB, mh)                                                         \
    _Pragma("unroll") for (int m = 0; m < 4; ++m) {                           \
        af[m][0] = LDA(DB, (mh) * 4 + m, 0);                                  \
        af[m][1] = LDA(DB, (mh) * 4 + m, 1); }
#define RD_BFA(DB)                                                            \
    _Pragma("unroll") for (int n = 0; n < 2; ++n) {                           \
        bfa[n][0] = LDB(DB, n, 0); bfa[n][1] = LDB(DB, n, 1); }
#define RD_BFB(DB)                                                            \
    _Pragma("unroll") for (int n = 0; n < 2; ++n) {                           \
        bfb[n][0] = LDB(DB, n + 2, 0); bfb[n][1] = LDB(DB, n + 2, 1); }

#define PAIR(CUR, OTH, s) do {                                                \
    /* P1: af<-CUR.A(m0-3); stage bA1(O)->OTH; Q(0,0)E */                     \
    RD_AF(CUR, 0);                                                            \
    STAGE_HALF(Xb, arow0 + 128, (s) + 1, (OTH) + 16384);                      \
    BARRIER(); LGKM0(); QMFMA(0, 0); BARRIER();                               \
    /* P2: bfb<-CUR.B(n2-3); stage bB1(O)->OTH; Q(0,1)E */                    \
    RD_BFB(CUR);                                                              \
    STAGE_HALF(Wb, brow0 + 128, (s) + 1, (OTH) + 49152);                      \
    BARRIER(); LGKM0(); QMFMA(0, 1); BARRIER();                               \
    /* P3: af<-CUR.A(m4-7); stage B0(E+2)->CUR; Q(1,0)E */                    \
    RD_AF(CUR, 1);                                                            \
    if ((s) + 2 < KT) STAGE_HALF(Wb, brow0, (s) + 2, (CUR) + 32768);          \
    BARRIER(); LGKM0(); QMFMA(1, 0); BARRIER();                               \
    /* P4: stage A0(E+2)->CUR; vmcnt; bfa<-OTH.B(n0-1); Q(1,1)E */            \
    if ((s) + 2 < KT) {                                                       \
        STAGE_HALF(Xb, arow0, (s) + 2, (CUR) + 0);                            \
        asm volatile("s_waitcnt vmcnt(4)" ::: "memory");                      \
    } else { asm volatile("s_waitcnt vmcnt(0)" ::: "memory"); }               \
    BARRIER();                                                                \
    RD_BFA(OTH);                                                              \
    QMFMA(1, 1); BARRIER();                                                   \
    /* P5: af<-OTH.A(m0-3); stage A1(E+2)->CUR; Q(0,0)O */                    \
    RD_AF(OTH, 0);                                                            \
    if ((s) + 2 < KT) STAGE_HALF(Xb, arow0 + 128, (s) + 2, (CUR) + 16384);    \
    BARRIER(); LGKM0(); QMFMA(0, 0); BARRIER();                               \
    /* P6: bfb<-OTH.B(n2-3); stage B1(E+2)->CUR; Q(0,1)O */                   \
    RD_BFB(OTH);                                                              \
    if ((s) + 2 < KT) STAGE_HALF(Wb, brow0 + 128, (s) + 2, (CUR) + 49152);    \
    BARRIER(); LGKM0(); QMFMA(0, 1); BARRIER();                               \
    /* P7: af<-OTH.A(m4-7); stage bB0(E+3)->OTH; Q(1,0)O */                   \
    RD_AF(OTH, 1);                                                            \
    if ((s) + 3 < KT) STAGE_HALF(Wb, brow0, (s) + 3, (OTH) + 32768);          \
    BARRIER(); LGKM0(); QMFMA(1, 0); BARRIER();                               \
    /* P8: stage bA0(E+3)->OTH; vmcnt; bfa<-CUR.B(n0-1) [tile E+2]; Q(1,1)O */\
    if ((s) + 3 < KT) {                                                       \
        STAGE_HALF(Xb, arow0, (s) + 3, (OTH) + 0);                            \
        asm volatile("s_waitcnt vmcnt(4)" ::: "memory");                      \
    } else { asm volatile("s_waitcnt vmcnt(0)" ::: "memory"); }               \
    BARRIER();                                                                \
    if ((s) + 2 < KT) { RD_BFA(CUR); }                                        \
    QMFMA(1, 1); BARRIER();                                                   \
} while (0)

    // ---- prologue: buf0 = tile0 (B0,A0,A1,B1), buf1 = bB0,bA0 of tile1 ----
    STAGE_HALF(Wb, brow0,       0, 32768);
    STAGE_HALF(Xb, arow0,       0, 0);
    STAGE_HALF(Xb, arow0 + 128, 0, 16384);
    STAGE_HALF(Wb, brow0 + 128, 0, 49152);
    STAGE_HALF(Wb, brow0,       1, 65536 + 32768);
    STAGE_HALF(Xb, arow0,       1, 65536 + 0);
    asm volatile("s_waitcnt vmcnt(4)" ::: "memory");
    BARRIER();
    RD_BFA(0);   // tile0's B(n0-1) from buf0

    for (int s = 0; s < KT; s += 2)
        PAIR(0, 65536, s);

    // ---- epilogue: C = acc + bias ----
#pragma unroll
    for (int n = 0; n < 4; ++n) {
        const int gcol = brow0 + wn * 64 + n * 16 + l15;
        const float bv = bias[gcol];
#pragma unroll
        for (int m = 0; m < 8; ++m) {
            const int grow = arow0 + wm * 128 + m * 16 + (lane >> 4) * 4;
#pragma unroll
            for (int rg = 0; rg < 4; ++rg)
                C[(grow + rg) * OUTF + gcol] = acc[m][n][rg] + bv;
        }
    }
#undef STAGE_HALF
#undef LDA
#undef LDB
#undef MFMA
#undef BARRIER
#undef LGKM0
#undef QMFMA
#undef RD_AF
#undef RD_BFA
#undef RD_BFB
#undef PAIR
}

// ---------------------------------------------------------------------------
extern "C" void kernel_launch(void* const* d_in, const int* in_sizes, int n_in,
                              void* d_out, int out_size, void* d_ws, size_t ws_size,
                              hipStream_t stream) {
    const float* x    = (const float*)d_in[0];   // [4,2048,4096]
    const float* bw   = (const float*)d_in[1];   // [4096,4096]
    const float* bb   = (const float*)d_in[2];   // [4096]
    const float* spec = (const float*)d_in[3];   // [10000]
    const float* ha   = (const float*)d_in[4];   // [16,4096]
    const int*   idx  = (const int*)d_in[5];     // [10000]
    float* out = (float*)d_out;

    char* ws = (char*)d_ws;
    float*          Bbuf = (float*)ws;                                // 256 KB
    unsigned short* Wb   = (unsigned short*)(ws + 262144);            // 32 MB
    unsigned short* Xb   = (unsigned short*)(ws + 262144 + 33554432); // 64 MB
    int2*           cjk2 = (int2*)(ws + 262144 + 33554432 + 67108864);// 128 KB
    int*            boff = (int*)(ws + 262144 + 33554432 + 67108864 + 131072);

    compact_sort_kernel<<<4, 256, 0, stream>>>(spec, idx, cjk2, boff);
    buildB_cvt_kernel<<<2048, 256, 0, stream>>>(cjk2, boff, Bbuf,
                                                (const float4*)x, (uint2*)Xb);
    build_w_kernel<<<512, 256, 0, stream>>>(bw, ha, Bbuf, Wb);
    gemm256_kernel<<<512, 512, 0, stream>>>(Xb, Wb, bb, out);
}